// Round 10
// baseline (198.027 us; speedup 1.0000x reference)
//
#include <hip/hip_runtime.h>

typedef float f32x4 __attribute__((ext_vector_type(4)));
typedef __bf16 bf16x8 __attribute__((ext_vector_type(8)));
typedef __bf16 bf16x4 __attribute__((ext_vector_type(4)));

constexpr float INV_SQRT_F = 0.17677669529663687f;  // 32^-0.5

__device__ __forceinline__ f32x4 mfma16(bf16x8 a, bf16x8 b) {
  const f32x4 z = {0.f, 0.f, 0.f, 0.f};
  return __builtin_amdgcn_mfma_f32_16x16x32_bf16(a, b, z, 0, 0, 0);
}
__device__ __forceinline__ f32x4 ld4(const float* p) {
  return *reinterpret_cast<const f32x4*>(p);
}
__device__ __forceinline__ bf16x4 ldb4(const __bf16* p) {
  return *reinterpret_cast<const bf16x4*>(p);
}
__device__ __forceinline__ f32x4 b2f4(bf16x4 v) {
  f32x4 r;
  r[0] = (float)v[0]; r[1] = (float)v[1]; r[2] = (float)v[2]; r[3] = (float)v[3];
  return r;
}
__device__ __forceinline__ bf16x4 f2b4(f32x4 v) {
  bf16x4 r;
  r[0] = (__bf16)v[0]; r[1] = (__bf16)v[1]; r[2] = (__bf16)v[2]; r[3] = (__bf16)v[3];
  return r;
}
__device__ __forceinline__ bf16x8 cvt_frag(f32x4 u, f32x4 v) {
  bf16x8 r;
  r[0] = (__bf16)u[0]; r[1] = (__bf16)u[1]; r[2] = (__bf16)u[2]; r[3] = (__bf16)u[3];
  r[4] = (__bf16)v[0]; r[5] = (__bf16)v[1]; r[6] = (__bf16)v[2]; r[7] = (__bf16)v[3];
  return r;
}

// T layout per node (1728 bf16, 3456 B), INV_SQRT_F folded into W:
//   [0,96):    l0 paths p0,p1,p2            : a*32
//   [96,576):  l1 paths p3,p5,p6,p7,p9      : 96 + b*96 + s*32
//   [576,1728):l2 paths p4,p8,p10,p11       : 576 + d*288 + ss*32
// Node-major so pass-2's 8 threads/edge consume all 27 lines of the node.

// ---------------- Pass 1: per-node transforms (MFMA) -----------------------
// Wave = 16 nodes. A = W frag (row = out-feature), B = h frag (col = node).
// D: lane(eidx,q) holds f32x4 = ht[node eidx][f = 16h+4q .. +3].
// Compute-and-store per (path, spatial, half): no accumulator array.
__global__ __launch_bounds__(256, 2)
void node_transform(const float* __restrict__ h0, const float* __restrict__ h1,
                    const float* __restrict__ h2, const float* __restrict__ Wg,
                    __bf16* __restrict__ T, int N)
{
  __shared__ bf16x8 wlds[12 * 2 * 4 * 16];
  for (int c = threadIdx.x; c < 12 * 2 * 4 * 16; c += 256) {
    const int gl = c & 15;
    const int qq = (c >> 4) & 3;
    const int hf = (c >> 6) & 1;
    const int p  = c >> 7;
    const float* wp = Wg + (p * 32 + hf * 16 + gl) * 32 + qq * 8;
    bf16x8 f;
#pragma unroll
    for (int j = 0; j < 8; ++j) f[j] = (__bf16)(wp[j] * INV_SQRT_F);
    wlds[c] = f;
  }
  __syncthreads();

  const int lane = threadIdx.x & 63;
  const int wid  = threadIdx.x >> 6;
  const int eidx = lane & 15;   // node within tile (B col / D col)
  const int q    = lane >> 4;   // k-chunk / D feature-quad
  int nb = (blockIdx.x * 4 + wid) * 16;
  if (nb > N - 16) nb = N - 16;
  const int node = nb + eidx;
  const int k0 = q * 8;

  // batch-issue h loads (f32), then convert
  const float* h0p = h0 + (long long)node * 32 + k0;
  const float* h1p = h1 + (long long)node * 96 + k0;
  const float* h2p = h2 + (long long)node * 288 + k0;
  f32x4 r0a = ld4(h0p), r0b = ld4(h0p + 4);
  f32x4 r1[6];
#pragma unroll
  for (int s = 0; s < 3; ++s) { r1[2*s] = ld4(h1p + s*32); r1[2*s+1] = ld4(h1p + s*32 + 4); }
  f32x4 r2[18];
#pragma unroll
  for (int s = 0; s < 9; ++s) { r2[2*s] = ld4(h2p + s*32); r2[2*s+1] = ld4(h2p + s*32 + 4); }

  const bf16x8 b0 = cvt_frag(r0a, r0b);
  bf16x8 b1[3];
#pragma unroll
  for (int s = 0; s < 3; ++s) b1[s] = cvt_frag(r1[2*s], r1[2*s+1]);
  bf16x8 b2[9];
#pragma unroll
  for (int s = 0; s < 9; ++s) b2[s] = cvt_frag(r2[2*s], r2[2*s+1]);

  __bf16* tn = T + (long long)node * 1728;

#define WF(P, H) (wlds[(((P) * 2 + (H)) * 4 + q) * 16 + eidx])
#define ST(OFF, V) *reinterpret_cast<bf16x4*>(tn + (OFF) + fo) = f2b4(V)

  const int l1p[5] = {3, 5, 6, 7, 9};
  const int l2p[4] = {4, 8, 10, 11};
#pragma unroll
  for (int h = 0; h < 2; ++h) {
    const int fo = 16 * h + 4 * q;
    ST(0 * 32, mfma16(WF(0, h), b0));
    ST(1 * 32, mfma16(WF(1, h), b0));
    ST(2 * 32, mfma16(WF(2, h), b0));
#pragma unroll
    for (int b = 0; b < 5; ++b)
#pragma unroll
      for (int s = 0; s < 3; ++s)
        ST(96 + b * 96 + s * 32, mfma16(WF(l1p[b], h), b1[s]));
#pragma unroll
    for (int d = 0; d < 4; ++d)
#pragma unroll
      for (int ss = 0; ss < 9; ++ss)
        ST(576 + d * 288 + ss * 32, mfma16(WF(l2p[d], h), b2[ss]));
  }
#undef ST
#undef WF
}

// ---------------- Pass 2: edge geometry (pure streaming, no MFMA/LDS) -----
// Thread = (edge, feature-quad c in 0..7). 8 threads/edge consume the full
// node T record (27 lines) and full g/out lines. acc = 13 f32x4 only.
__global__ __launch_bounds__(256, 3)
void edge_geometry(const __bf16* __restrict__ T, const float* __restrict__ g0,
                   const float* __restrict__ g1, const float* __restrict__ g2,
                   const int* __restrict__ src, float* __restrict__ out, int E)
{
  const int i = blockIdx.x * 256 + threadIdx.x;
  const int e = i >> 3;
  if (e >= E) return;
  const int fo = (i & 7) * 4;

  const int node = src[e];
  const float* gp0 = g0 + (long long)e * 32 + fo;
  const float* gp1 = g1 + (long long)e * 96 + fo;
  const float* gp2 = g2 + (long long)e * 288 + fo;
  const __bf16* tn = T + (long long)node * 1728 + fo;

  // ---- g loads first (HBM latency), 10 lines in flight
  const f32x4 gv0 = ld4(gp0);
  f32x4 gv1[3];
#pragma unroll
  for (int s = 0; s < 3; ++s) gv1[s] = ld4(gp1 + s * 32);
  f32x4 gkA[3], gkB[3];
#pragma unroll
  for (int j = 0; j < 3; ++j) gkA[j] = ld4(gp2 + j * 32);
#pragma unroll
  for (int j = 0; j < 3; ++j) gkB[j] = ld4(gp2 + (3 + j) * 32);

  // ---- phase g0: p0->acc0, p3->acc1, p4->acc2 (accs initialized here)
  f32x4 acc0 = b2f4(ldb4(tn + 0)) * gv0;
  f32x4 acc1[3];
#pragma unroll
  for (int s = 0; s < 3; ++s) acc1[s] = b2f4(ldb4(tn + 96 + s * 32)) * gv0;
  f32x4 acc2[9];
#pragma unroll
  for (int ss = 0; ss < 9; ++ss) acc2[ss] = b2f4(ldb4(tn + 576 + ss * 32)) * gv0;

  // ---- phase g1: p1 (prod), p5 (dot), p6 (cross), p7 (outer), p8 (mat_vec)
  {
    const f32x4 h1v = b2f4(ldb4(tn + 32));                    // p1
#pragma unroll
    for (int s = 0; s < 3; ++s) acc1[s] += h1v * gv1[s];
  }
#pragma unroll
  for (int s = 0; s < 3; ++s)                                  // p5
    acc0 += b2f4(ldb4(tn + 192 + s * 32)) * gv1[s];
  {
    f32x4 h6[3];                                               // p6
#pragma unroll
    for (int s = 0; s < 3; ++s) h6[s] = b2f4(ldb4(tn + 288 + s * 32));
    acc1[0] += h6[1] * gv1[2] - h6[2] * gv1[1];
    acc1[1] += h6[2] * gv1[0] - h6[0] * gv1[2];
    acc1[2] += h6[0] * gv1[1] - h6[1] * gv1[0];
  }
  {
    f32x4 h7[3];                                               // p7 (outer)
#pragma unroll
    for (int s = 0; s < 3; ++s) h7[s] = b2f4(ldb4(tn + 384 + s * 32));
    const f32x4 tr3 = (h7[0] * gv1[0] + h7[1] * gv1[1] + h7[2] * gv1[2]) * (1.f / 3.f);
#pragma unroll
    for (int a = 0; a < 3; ++a)
#pragma unroll
      for (int b = 0; b < 3; ++b) acc2[a * 3 + b] += h7[a] * gv1[b];
    acc2[0] -= tr3; acc2[4] -= tr3; acc2[8] -= tr3;
  }
#pragma unroll
  for (int a = 0; a < 3; ++a)                                  // p8 (mat_vec)
#pragma unroll
    for (int b = 0; b < 3; ++b)
      acc1[a] += b2f4(ldb4(tn + 864 + (a * 3 + b) * 32)) * gv1[b];

  // ---- phase g2: p2 (prod), p9 (vec_mat), p10 (double_dot), p11 (sym)
  const f32x4 h2v = b2f4(ldb4(tn + 64));                       // p2, reused 9x
  f32x4 h9[3];                                                 // p9, reused
#pragma unroll
  for (int s = 0; s < 3; ++s) h9[s] = b2f4(ldb4(tn + 480 + s * 32));

#define G2ROW(K, GK)                                                           \
  {                                                                            \
    _Pragma("unroll")                                                          \
    for (int j = 0; j < 3; ++j) acc2[(K) * 3 + j] += h2v * GK[j];              \
    _Pragma("unroll")                                                          \
    for (int j = 0; j < 3; ++j) acc1[j] += h9[(K)] * GK[j];                    \
    _Pragma("unroll")                                                          \
    for (int j = 0; j < 3; ++j)                                                \
      acc0 += b2f4(ldb4(tn + 1152 + ((K) * 3 + j) * 32)) * GK[j];              \
    {                                                                          \
      const f32x4 m0 = b2f4(ldb4(tn + 1440 + (0 * 3 + (K)) * 32));             \
      const f32x4 m1 = b2f4(ldb4(tn + 1440 + (1 * 3 + (K)) * 32));             \
      const f32x4 m2 = b2f4(ldb4(tn + 1440 + (2 * 3 + (K)) * 32));             \
      const f32x4 tk3 = (m0 * GK[0] + m1 * GK[1] + m2 * GK[2]) * (1.f / 3.f);  \
      acc2[0] += m0 * GK[0] - tk3;                                             \
      acc2[4] += m1 * GK[1] - tk3;                                             \
      acc2[8] += m2 * GK[2] - tk3;                                             \
      const f32x4 s01 = (m0 * GK[1] + m1 * GK[0]) * 0.5f;                      \
      acc2[1] += s01; acc2[3] += s01;                                          \
      const f32x4 s02 = (m0 * GK[2] + m2 * GK[0]) * 0.5f;                      \
      acc2[2] += s02; acc2[6] += s02;                                          \
      const f32x4 s12 = (m1 * GK[2] + m2 * GK[1]) * 0.5f;                      \
      acc2[5] += s12; acc2[7] += s12;                                          \
    }                                                                          \
  }

  G2ROW(0, gkA)
  // roll: load g2 row 2 into gkA slot
#pragma unroll
  for (int j = 0; j < 3; ++j) gkA[j] = ld4(gp2 + (6 + j) * 32);
  G2ROW(1, gkB)
  G2ROW(2, gkA)
#undef G2ROW

  // ---- stores (8 threads/edge cover every line fully)
  float* o0p = out + (long long)e * 32 + fo;
  float* o1p = out + (long long)E * 32 + (long long)e * 96 + fo;
  float* o2p = out + (long long)E * 128 + (long long)e * 288 + fo;
  *reinterpret_cast<f32x4*>(o0p) = acc0;
#pragma unroll
  for (int s = 0; s < 3; ++s) *reinterpret_cast<f32x4*>(o1p + s * 32) = acc1[s];
#pragma unroll
  for (int s = 0; s < 9; ++s) *reinterpret_cast<f32x4*>(o2p + s * 32) = acc2[s];
}

// ---------------- fallback: R5 kernel (127 us, known-good), no ws ---------
__device__ __forceinline__ bf16x8 load_frag8(const float* __restrict__ p) {
  return cvt_frag(ld4(p), ld4(p + 4));
}
__device__ __forceinline__ f32x4 ntload4(const float* __restrict__ p) {
  return __builtin_nontemporal_load(reinterpret_cast<const f32x4*>(p));
}
__device__ __forceinline__ void ntstore4(float* __restrict__ p, f32x4 v) {
  __builtin_nontemporal_store(v, reinterpret_cast<f32x4*>(p));
}

__global__ __launch_bounds__(256, 2)
void leibniz_fused(const float* __restrict__ h0, const float* __restrict__ h1,
                   const float* __restrict__ h2, const float* __restrict__ g0,
                   const float* __restrict__ g1, const float* __restrict__ g2,
                   const float* __restrict__ Wg, const int* __restrict__ src,
                   float* __restrict__ out, int E)
{
  __shared__ bf16x8 wlds[12 * 2 * 4 * 16];
  for (int c = threadIdx.x; c < 12 * 2 * 4 * 16; c += 256) {
    const int gl = c & 15;
    const int qq = (c >> 4) & 3;
    const int hf = (c >> 6) & 1;
    const int p  = c >> 7;
    const float* wp = Wg + (p * 32 + hf * 16 + gl) * 32 + qq * 8;
    bf16x8 f;
#pragma unroll
    for (int j = 0; j < 8; ++j) f[j] = (__bf16)(wp[j] * INV_SQRT_F);
    wlds[c] = f;
  }
  __syncthreads();

  const int lane = threadIdx.x & 63;
  const int wid  = threadIdx.x >> 6;
  const int eidx = lane & 15;
  const int q    = lane >> 4;
  int e0 = (blockIdx.x * 4 + wid) * 16;
  if (e0 > E - 16) e0 = E - 16;

  const int node = src[e0 + eidx];
  const int e   = e0 + eidx;
  const int col = q * 4;
  const float* g0p = g0 + e * 32 + col;
  const float* g1p = g1 + (long long)e * 96 + col;
  const float* g2p = g2 + (long long)e * 288 + col;

  f32x4 gv0[2];
  gv0[0] = ntload4(g0p); gv0[1] = ntload4(g0p + 16);
  f32x4 gv1[3][2];
#pragma unroll
  for (int s = 0; s < 3; ++s) {
    gv1[s][0] = ntload4(g1p + s * 32);
    gv1[s][1] = ntload4(g1p + s * 32 + 16);
  }

  const int k0 = q * 8;
  const bf16x8 b0 = load_frag8(h0 + node * 32 + k0);
  bf16x8 b1[3];
#pragma unroll
  for (int s = 0; s < 3; ++s) b1[s] = load_frag8(h1 + node * 96 + s * 32 + k0);
  bf16x8 b2[9];
#pragma unroll
  for (int s = 0; s < 9; ++s) b2[s] = load_frag8(h2 + node * 288 + s * 32 + k0);

  const f32x4 z4 = {0.f, 0.f, 0.f, 0.f};
  f32x4 acc0[2] = {z4, z4};
  f32x4 acc1[3][2];
  f32x4 acc2[9][2];
#pragma unroll
  for (int s = 0; s < 3; ++s) { acc1[s][0] = z4; acc1[s][1] = z4; }
#pragma unroll
  for (int s = 0; s < 9; ++s) { acc2[s][0] = z4; acc2[s][1] = z4; }

#define WFRAG(P, H) (wlds[(((P) * 2 + (H)) * 4 + q) * 16 + eidx])
#pragma unroll
  for (int h = 0; h < 2; ++h) {
    acc0[h] += mfma16(WFRAG(0, h), b0) * gv0[h];
    const bf16x8 w3 = WFRAG(3, h);
#pragma unroll
    for (int s = 0; s < 3; ++s) acc1[s][h] += mfma16(w3, b1[s]) * gv0[h];
    const bf16x8 w4 = WFRAG(4, h);
#pragma unroll
    for (int s = 0; s < 9; ++s) acc2[s][h] += mfma16(w4, b2[s]) * gv0[h];
  }

  f32x4 gkA[3][2];
#pragma unroll
  for (int j = 0; j < 3; ++j) {
    gkA[j][0] = ntload4(g2p + j * 32);
    gkA[j][1] = ntload4(g2p + j * 32 + 16);
  }

#pragma unroll
  for (int h = 0; h < 2; ++h) {
    {
      const f32x4 t = mfma16(WFRAG(1, h), b0);
#pragma unroll
      for (int s = 0; s < 3; ++s) acc1[s][h] += t * gv1[s][h];
    }
    {
      const bf16x8 w5 = WFRAG(5, h);
#pragma unroll
      for (int s = 0; s < 3; ++s) acc0[h] += mfma16(w5, b1[s]) * gv1[s][h];
    }
    {
      const bf16x8 w6 = WFRAG(6, h);
      const f32x4 c0 = mfma16(w6, b1[0]);
      const f32x4 c1 = mfma16(w6, b1[1]);
      const f32x4 c2 = mfma16(w6, b1[2]);
      acc1[0][h] += c1 * gv1[2][h] - c2 * gv1[1][h];
      acc1[1][h] += c2 * gv1[0][h] - c0 * gv1[2][h];
      acc1[2][h] += c0 * gv1[1][h] - c1 * gv1[0][h];
    }
    {
      const bf16x8 w7 = WFRAG(7, h);
      const f32x4 o0 = mfma16(w7, b1[0]);
      const f32x4 o1 = mfma16(w7, b1[1]);
      const f32x4 o2 = mfma16(w7, b1[2]);
      const f32x4 tr3 = (o0 * gv1[0][h] + o1 * gv1[1][h] + o2 * gv1[2][h]) * (1.f / 3.f);
      acc2[0][h] += o0 * gv1[0][h] - tr3;
      acc2[1][h] += o0 * gv1[1][h];
      acc2[2][h] += o0 * gv1[2][h];
      acc2[3][h] += o1 * gv1[0][h];
      acc2[4][h] += o1 * gv1[1][h] - tr3;
      acc2[5][h] += o1 * gv1[2][h];
      acc2[6][h] += o2 * gv1[0][h];
      acc2[7][h] += o2 * gv1[1][h];
      acc2[8][h] += o2 * gv1[2][h] - tr3;
    }
    {
      const bf16x8 w8 = WFRAG(8, h);
#pragma unroll
      for (int a = 0; a < 3; ++a)
#pragma unroll
        for (int b = 0; b < 3; ++b)
          acc1[a][h] += mfma16(w8, b2[a * 3 + b]) * gv1[b][h];
    }
  }

  f32x4 gkB[3][2];
#pragma unroll
  for (int j = 0; j < 3; ++j) {
    gkB[j][0] = ntload4(g2p + (3 + j) * 32);
    gkB[j][1] = ntload4(g2p + (3 + j) * 32 + 16);
  }

  f32x4 t2[2];
  t2[0] = mfma16(WFRAG(2, 0), b0);
  t2[1] = mfma16(WFRAG(2, 1), b0);

#define G2ROW_COMPUTE(K, GK)                                                   \
  {                                                                            \
    _Pragma("unroll")                                                          \
    for (int h = 0; h < 2; ++h) {                                              \
      _Pragma("unroll")                                                        \
      for (int j = 0; j < 3; ++j) acc2[(K) * 3 + j][h] += t2[h] * GK[j][h];    \
      {                                                                        \
        const f32x4 vk = mfma16(WFRAG(9, h), b1[(K)]);                         \
        _Pragma("unroll")                                                      \
        for (int j = 0; j < 3; ++j) acc1[j][h] += vk * GK[j][h];               \
      }                                                                        \
      {                                                                        \
        const bf16x8 w10 = WFRAG(10, h);                                       \
        _Pragma("unroll")                                                      \
        for (int j = 0; j < 3; ++j)                                            \
          acc0[h] += mfma16(w10, b2[(K) * 3 + j]) * GK[j][h];                  \
      }                                                                        \
      {                                                                        \
        const bf16x8 w11 = WFRAG(11, h);                                       \
        const f32x4 m0 = mfma16(w11, b2[0 * 3 + (K)]);                         \
        const f32x4 m1 = mfma16(w11, b2[1 * 3 + (K)]);                         \
        const f32x4 m2 = mfma16(w11, b2[2 * 3 + (K)]);                         \
        const f32x4 tk3 =                                                      \
            (m0 * GK[0][h] + m1 * GK[1][h] + m2 * GK[2][h]) * (1.f / 3.f);     \
        acc2[0][h] += m0 * GK[0][h] - tk3;                                     \
        acc2[4][h] += m1 * GK[1][h] - tk3;                                     \
        acc2[8][h] += m2 * GK[2][h] - tk3;                                     \
        const f32x4 s01 = (m0 * GK[1][h] + m1 * GK[0][h]) * 0.5f;              \
        acc2[1][h] += s01; acc2[3][h] += s01;                                  \
        const f32x4 s02 = (m0 * GK[2][h] + m2 * GK[0][h]) * 0.5f;              \
        acc2[2][h] += s02; acc2[6][h] += s02;                                  \
        const f32x4 s12 = (m1 * GK[2][h] + m2 * GK[1][h]) * 0.5f;              \
        acc2[5][h] += s12; acc2[7][h] += s12;                                  \
      }                                                                        \
    }                                                                          \
  }

  G2ROW_COMPUTE(0, gkA)
#pragma unroll
  for (int j = 0; j < 3; ++j) {
    gkA[j][0] = ntload4(g2p + (6 + j) * 32);
    gkA[j][1] = ntload4(g2p + (6 + j) * 32 + 16);
  }
  G2ROW_COMPUTE(1, gkB)
  G2ROW_COMPUTE(2, gkA)
#undef G2ROW_COMPUTE

  float* o0p = out + (long long)e * 32 + col;
  float* o1p = out + (long long)E * 32 + (long long)e * 96 + col;
  float* o2p = out + (long long)E * 128 + (long long)e * 288 + col;
  ntstore4(o0p, acc0[0]);
  ntstore4(o0p + 16, acc0[1]);
#pragma unroll
  for (int s = 0; s < 3; ++s) {
    ntstore4(o1p + s * 32, acc1[s][0]);
    ntstore4(o1p + s * 32 + 16, acc1[s][1]);
  }
#pragma unroll
  for (int s = 0; s < 9; ++s) {
    ntstore4(o2p + s * 32, acc2[s][0]);
    ntstore4(o2p + s * 32 + 16, acc2[s][1]);
  }
#undef WFRAG
}

extern "C" void kernel_launch(void* const* d_in, const int* in_sizes, int n_in,
                              void* d_out, int out_size, void* d_ws, size_t ws_size,
                              hipStream_t stream) {
  const float* h0 = (const float*)d_in[0];
  const float* h1 = (const float*)d_in[1];
  const float* h2 = (const float*)d_in[2];
  const float* g0 = (const float*)d_in[3];
  const float* g1 = (const float*)d_in[4];
  const float* g2 = (const float*)d_in[5];
  const float* Wg = (const float*)d_in[6];
  const int* src = (const int*)d_in[7];  // harness passes integer inputs as int32
  const int E = in_sizes[7];
  const int N = in_sizes[0] / 32;

  const size_t need = (size_t)N * 1728 * 2;  // bf16 node-transform table
  if (ws_size >= need) {
    __bf16* T = (__bf16*)d_ws;
    node_transform<<<(N + 63) / 64, 256, 0, stream>>>(h0, h1, h2, Wg, T, N);
    edge_geometry<<<(E * 8 + 255) / 256, 256, 0, stream>>>(T, g0, g1, g2, src,
                                                           (float*)d_out, E);
  } else {
    leibniz_fused<<<(E + 63) / 64, 256, 0, stream>>>(h0, h1, h2, g0, g1, g2,
                                                     Wg, src, (float*)d_out, E);
  }
}

// Round 11
// 141.052 us; speedup vs baseline: 1.4039x; 1.4039x over previous
//
#include <hip/hip_runtime.h>

typedef float f32x4 __attribute__((ext_vector_type(4)));
typedef __bf16 bf16x8 __attribute__((ext_vector_type(8)));
typedef __bf16 bf16x4 __attribute__((ext_vector_type(4)));

constexpr float INV_SQRT_F = 0.17677669529663687f;  // 32^-0.5

__device__ __forceinline__ f32x4 mfma16(bf16x8 a, bf16x8 b) {
  const f32x4 z = {0.f, 0.f, 0.f, 0.f};
  return __builtin_amdgcn_mfma_f32_16x16x32_bf16(a, b, z, 0, 0, 0);
}
__device__ __forceinline__ f32x4 ld4(const float* p) {
  return *reinterpret_cast<const f32x4*>(p);
}
__device__ __forceinline__ bf16x8 ldb8(const __bf16* __restrict__ p) {
  return *reinterpret_cast<const bf16x8*>(p);
}
__device__ __forceinline__ bf16x8 cvt_frag(f32x4 u, f32x4 v) {
  bf16x8 r;
  r[0] = (__bf16)u[0]; r[1] = (__bf16)u[1]; r[2] = (__bf16)u[2]; r[3] = (__bf16)u[3];
  r[4] = (__bf16)v[0]; r[5] = (__bf16)v[1]; r[6] = (__bf16)v[2]; r[7] = (__bf16)v[3];
  return r;
}

// ---------------- pre-pass: h -> bf16, W -> scaled frag-layout bf16 --------
// ws layout: [0,24576)B W frags (1536 x bf16x8); then hb0|hb1|hb2 bf16.
__global__ __launch_bounds__(256)
void leibniz_prepass(const float* __restrict__ h0, const float* __restrict__ h1,
                     const float* __restrict__ h2, const float* __restrict__ Wg,
                     __bf16* __restrict__ ws, int n0, int n1, int n2)
{
  if (blockIdx.x == 0) {
    bf16x8* wsW = reinterpret_cast<bf16x8*>(ws);
    for (int c = threadIdx.x; c < 12 * 2 * 4 * 16; c += 256) {
      const int gl = c & 15;
      const int qq = (c >> 4) & 3;
      const int hf = (c >> 6) & 1;
      const int p  = c >> 7;
      const float* wp = Wg + (p * 32 + hf * 16 + gl) * 32 + qq * 8;
      bf16x8 f;
#pragma unroll
      for (int j = 0; j < 8; ++j) f[j] = (__bf16)(wp[j] * INV_SQRT_F);
      wsW[c] = f;
    }
  }
  __bf16* hb0 = ws + 12288;
  __bf16* hb1 = hb0 + n0;
  __bf16* hb2 = hb1 + n1;
  const int q0 = n0 >> 2, q1 = n1 >> 2, q2 = n2 >> 2;
  const int total = q0 + q1 + q2;
  for (int i = blockIdx.x * 256 + threadIdx.x; i < total; i += gridDim.x * 256) {
    const float* sp;
    __bf16* dp;
    if (i < q0)           { sp = h0 + 4 * i;              dp = hb0 + 4 * i; }
    else if (i < q0 + q1) { int j = i - q0;      sp = h1 + 4 * j; dp = hb1 + 4 * j; }
    else                  { int j = i - q0 - q1; sp = h2 + 4 * j; dp = hb2 + 4 * j; }
    const f32x4 v = *reinterpret_cast<const f32x4*>(sp);
    bf16x4 o;
    o[0] = (__bf16)v[0]; o[1] = (__bf16)v[1]; o[2] = (__bf16)v[2]; o[3] = (__bf16)v[3];
    *reinterpret_cast<bf16x4*>(dp) = o;
  }
}

// ---------------- main: half-split wave, fully batched loads ---------------
// Waves (2t, 2t+1) of a block: SAME 16-edge tile, parity = feature half.
// Per wave: issue 13 g f32x4 loads + 13 h bf16x8 frag loads (ws) back-to-back
// -> ONE long-latency wait -> 54 MFMAs + geometry into 13 f32x4 accs -> 13
// stores. acc 52 + g 52 + h 52 regs fits (256,2) with no spill — the first
// structure where full batching is register-feasible (R7/R8 spilled at
// dual-half; R6 was unbatched). Pair waves share the block (same XCD L2) so
// the two 64B sectors of each g/out line merge; s_barrier aligns stores.
__global__ __launch_bounds__(256, 2)
void leibniz_half(const __bf16* __restrict__ wsAll,
                  const float* __restrict__ g0, const float* __restrict__ g1,
                  const float* __restrict__ g2, const int* __restrict__ src,
                  float* __restrict__ out, int E, int n0, int n1)
{
  __shared__ bf16x8 wlds[12 * 2 * 4 * 16];
  {
    const bf16x8* wsW = reinterpret_cast<const bf16x8*>(wsAll);
    for (int c = threadIdx.x; c < 12 * 2 * 4 * 16; c += 256) wlds[c] = wsW[c];
  }
  __syncthreads();

  const __bf16* hb0 = wsAll + 12288;
  const __bf16* hb1 = hb0 + n0;
  const __bf16* hb2 = hb1 + n1;

  const int lane = threadIdx.x & 63;
  const int wid  = threadIdx.x >> 6;
  const int half = wid & 1;     // feature half owned by this wave
  const int tile = wid >> 1;    // edge tile within block
  const int eidx = lane & 15;   // edge within tile
  const int q    = lane >> 4;   // feature quad (within half)
  int e0 = (blockIdx.x * 2 + tile) * 16;
  if (e0 > E - 16) e0 = E - 16;

  const int node = src[e0 + eidx];
  const int e    = e0 + eidx;
  const int col  = q * 4 + 16 * half;

  // ---- batch-issue ALL loads: g first (HBM), then h (ws, L3-resident)
  const float* g0p = g0 + (long long)e * 32 + col;
  const float* g1p = g1 + (long long)e * 96 + col;
  const float* g2p = g2 + (long long)e * 288 + col;
  const f32x4 gv0 = ld4(g0p);
  f32x4 gv1[3];
#pragma unroll
  for (int s = 0; s < 3; ++s) gv1[s] = ld4(g1p + s * 32);
  f32x4 gk[9];
#pragma unroll
  for (int s = 0; s < 9; ++s) gk[s] = ld4(g2p + s * 32);

  const int k0 = q * 8;
  const bf16x8 b0 = ldb8(hb0 + (long long)node * 32 + k0);
  bf16x8 b1[3];
#pragma unroll
  for (int s = 0; s < 3; ++s) b1[s] = ldb8(hb1 + (long long)node * 96 + s * 32 + k0);
  bf16x8 b2[9];
#pragma unroll
  for (int s = 0; s < 9; ++s) b2[s] = ldb8(hb2 + (long long)node * 288 + s * 32 + k0);

#define WFRAG(P) (wlds[(((P) * 2 + half) * 4 + q) * 16 + eidx])

  // ---- g0 phase: paths 0 (0,0->0), 3 (1,0->1), 4 (2,0->2), all 'prod'
  f32x4 acc0 = mfma16(WFRAG(0), b0) * gv0;
  f32x4 acc1[3];
  f32x4 acc2[9];
  {
    const bf16x8 w3 = WFRAG(3);
#pragma unroll
    for (int s = 0; s < 3; ++s) acc1[s] = mfma16(w3, b1[s]) * gv0;
    const bf16x8 w4 = WFRAG(4);
#pragma unroll
    for (int s = 0; s < 9; ++s) acc2[s] = mfma16(w4, b2[s]) * gv0;
  }

  // ---- g1 phase: paths 1 (prod), 5 (dot), 6 (cross), 7 (outer), 8 (mat_vec)
  {
    const f32x4 t = mfma16(WFRAG(1), b0);
#pragma unroll
    for (int s = 0; s < 3; ++s) acc1[s] += t * gv1[s];
  }
  {
    const bf16x8 w5 = WFRAG(5);
#pragma unroll
    for (int s = 0; s < 3; ++s) acc0 += mfma16(w5, b1[s]) * gv1[s];
  }
  {
    const bf16x8 w6 = WFRAG(6);
    const f32x4 c0 = mfma16(w6, b1[0]);
    const f32x4 c1 = mfma16(w6, b1[1]);
    const f32x4 c2 = mfma16(w6, b1[2]);
    acc1[0] += c1 * gv1[2] - c2 * gv1[1];
    acc1[1] += c2 * gv1[0] - c0 * gv1[2];
    acc1[2] += c0 * gv1[1] - c1 * gv1[0];
  }
  {
    const bf16x8 w7 = WFRAG(7);
    const f32x4 o0 = mfma16(w7, b1[0]);
    const f32x4 o1 = mfma16(w7, b1[1]);
    const f32x4 o2 = mfma16(w7, b1[2]);
    const f32x4 tr3 = (o0 * gv1[0] + o1 * gv1[1] + o2 * gv1[2]) * (1.f / 3.f);
    acc2[0] += o0 * gv1[0] - tr3;
    acc2[1] += o0 * gv1[1];
    acc2[2] += o0 * gv1[2];
    acc2[3] += o1 * gv1[0];
    acc2[4] += o1 * gv1[1] - tr3;
    acc2[5] += o1 * gv1[2];
    acc2[6] += o2 * gv1[0];
    acc2[7] += o2 * gv1[1];
    acc2[8] += o2 * gv1[2] - tr3;
  }
  {
    const bf16x8 w8 = WFRAG(8);
#pragma unroll
    for (int a = 0; a < 3; ++a)
#pragma unroll
      for (int b = 0; b < 3; ++b)
        acc1[a] += mfma16(w8, b2[a * 3 + b]) * gv1[b];
  }

  // ---- g2 phase: paths 2 (prod), 9 (vec_mat), 10 (double_dot), 11 (sym)
  {
    const f32x4 t2 = mfma16(WFRAG(2), b0);
#pragma unroll
    for (int ss = 0; ss < 9; ++ss) acc2[ss] += t2 * gk[ss];
  }
  {
    const bf16x8 w9 = WFRAG(9);
#pragma unroll
    for (int i = 0; i < 3; ++i) {
      const f32x4 vk = mfma16(w9, b1[i]);
#pragma unroll
      for (int j = 0; j < 3; ++j) acc1[j] += vk * gk[i * 3 + j];
    }
  }
  {
    const bf16x8 w10 = WFRAG(10);
#pragma unroll
    for (int ss = 0; ss < 9; ++ss) acc0 += mfma16(w10, b2[ss]) * gk[ss];
  }
  {
    const bf16x8 w11 = WFRAG(11);
#pragma unroll
    for (int k = 0; k < 3; ++k) {
      const f32x4 m0 = mfma16(w11, b2[0 * 3 + k]);
      const f32x4 m1 = mfma16(w11, b2[1 * 3 + k]);
      const f32x4 m2 = mfma16(w11, b2[2 * 3 + k]);
      const f32x4 gk0 = gk[k * 3 + 0];
      const f32x4 gk1 = gk[k * 3 + 1];
      const f32x4 gk2 = gk[k * 3 + 2];
      const f32x4 tk3 = (m0 * gk0 + m1 * gk1 + m2 * gk2) * (1.f / 3.f);
      acc2[0] += m0 * gk0 - tk3;
      acc2[4] += m1 * gk1 - tk3;
      acc2[8] += m2 * gk2 - tk3;
      const f32x4 s01 = (m0 * gk1 + m1 * gk0) * 0.5f;
      acc2[1] += s01; acc2[3] += s01;
      const f32x4 s02 = (m0 * gk2 + m2 * gk0) * 0.5f;
      acc2[2] += s02; acc2[6] += s02;
      const f32x4 s12 = (m1 * gk2 + m2 * gk1) * 0.5f;
      acc2[5] += s12; acc2[7] += s12;
    }
  }

  __builtin_amdgcn_s_barrier();  // align pair store bursts (sector merging)

  // ---- stores: 16B per (edge, spatial) row; pair covers both 64B sectors
  float* o0p = out + (long long)e * 32 + col;
  float* o1p = out + (long long)E * 32 + (long long)e * 96 + col;
  float* o2p = out + (long long)E * 128 + (long long)e * 288 + col;
  *reinterpret_cast<f32x4*>(o0p) = acc0;
#pragma unroll
  for (int s = 0; s < 3; ++s) *reinterpret_cast<f32x4*>(o1p + s * 32) = acc1[s];
#pragma unroll
  for (int s = 0; s < 9; ++s) *reinterpret_cast<f32x4*>(o2p + s * 32) = acc2[s];
#undef WFRAG
}

// ---------------- fallback: R5 kernel (127 us, known-good), no ws ---------
__device__ __forceinline__ bf16x8 load_frag8(const float* __restrict__ p) {
  return cvt_frag(ld4(p), ld4(p + 4));
}
__device__ __forceinline__ f32x4 ntload4(const float* __restrict__ p) {
  return __builtin_nontemporal_load(reinterpret_cast<const f32x4*>(p));
}
__device__ __forceinline__ void ntstore4(float* __restrict__ p, f32x4 v) {
  __builtin_nontemporal_store(v, reinterpret_cast<f32x4*>(p));
}

__global__ __launch_bounds__(256, 2)
void leibniz_fused(const float* __restrict__ h0, const float* __restrict__ h1,
                   const float* __restrict__ h2, const float* __restrict__ g0,
                   const float* __restrict__ g1, const float* __restrict__ g2,
                   const float* __restrict__ Wg, const int* __restrict__ src,
                   float* __restrict__ out, int E)
{
  __shared__ bf16x8 wlds[12 * 2 * 4 * 16];
  for (int c = threadIdx.x; c < 12 * 2 * 4 * 16; c += 256) {
    const int gl = c & 15;
    const int qq = (c >> 4) & 3;
    const int hf = (c >> 6) & 1;
    const int p  = c >> 7;
    const float* wp = Wg + (p * 32 + hf * 16 + gl) * 32 + qq * 8;
    bf16x8 f;
#pragma unroll
    for (int j = 0; j < 8; ++j) f[j] = (__bf16)(wp[j] * INV_SQRT_F);
    wlds[c] = f;
  }
  __syncthreads();

  const int lane = threadIdx.x & 63;
  const int wid  = threadIdx.x >> 6;
  const int eidx = lane & 15;
  const int q    = lane >> 4;
  int e0 = (blockIdx.x * 4 + wid) * 16;
  if (e0 > E - 16) e0 = E - 16;

  const int node = src[e0 + eidx];
  const int e   = e0 + eidx;
  const int col = q * 4;
  const float* g0p = g0 + e * 32 + col;
  const float* g1p = g1 + (long long)e * 96 + col;
  const float* g2p = g2 + (long long)e * 288 + col;

  f32x4 gv0[2];
  gv0[0] = ntload4(g0p); gv0[1] = ntload4(g0p + 16);
  f32x4 gv1[3][2];
#pragma unroll
  for (int s = 0; s < 3; ++s) {
    gv1[s][0] = ntload4(g1p + s * 32);
    gv1[s][1] = ntload4(g1p + s * 32 + 16);
  }

  const int k0 = q * 8;
  const bf16x8 b0 = load_frag8(h0 + node * 32 + k0);
  bf16x8 b1[3];
#pragma unroll
  for (int s = 0; s < 3; ++s) b1[s] = load_frag8(h1 + node * 96 + s * 32 + k0);
  bf16x8 b2[9];
#pragma unroll
  for (int s = 0; s < 9; ++s) b2[s] = load_frag8(h2 + node * 288 + s * 32 + k0);

  const f32x4 z4 = {0.f, 0.f, 0.f, 0.f};
  f32x4 acc0[2] = {z4, z4};
  f32x4 acc1[3][2];
  f32x4 acc2[9][2];
#pragma unroll
  for (int s = 0; s < 3; ++s) { acc1[s][0] = z4; acc1[s][1] = z4; }
#pragma unroll
  for (int s = 0; s < 9; ++s) { acc2[s][0] = z4; acc2[s][1] = z4; }

#define WFRAG(P, H) (wlds[(((P) * 2 + (H)) * 4 + q) * 16 + eidx])
#pragma unroll
  for (int h = 0; h < 2; ++h) {
    acc0[h] += mfma16(WFRAG(0, h), b0) * gv0[h];
    const bf16x8 w3 = WFRAG(3, h);
#pragma unroll
    for (int s = 0; s < 3; ++s) acc1[s][h] += mfma16(w3, b1[s]) * gv0[h];
    const bf16x8 w4 = WFRAG(4, h);
#pragma unroll
    for (int s = 0; s < 9; ++s) acc2[s][h] += mfma16(w4, b2[s]) * gv0[h];
  }

  f32x4 gkA[3][2];
#pragma unroll
  for (int j = 0; j < 3; ++j) {
    gkA[j][0] = ntload4(g2p + j * 32);
    gkA[j][1] = ntload4(g2p + j * 32 + 16);
  }

#pragma unroll
  for (int h = 0; h < 2; ++h) {
    {
      const f32x4 t = mfma16(WFRAG(1, h), b0);
#pragma unroll
      for (int s = 0; s < 3; ++s) acc1[s][h] += t * gv1[s][h];
    }
    {
      const bf16x8 w5 = WFRAG(5, h);
#pragma unroll
      for (int s = 0; s < 3; ++s) acc0[h] += mfma16(w5, b1[s]) * gv1[s][h];
    }
    {
      const bf16x8 w6 = WFRAG(6, h);
      const f32x4 c0 = mfma16(w6, b1[0]);
      const f32x4 c1 = mfma16(w6, b1[1]);
      const f32x4 c2 = mfma16(w6, b1[2]);
      acc1[0][h] += c1 * gv1[2][h] - c2 * gv1[1][h];
      acc1[1][h] += c2 * gv1[0][h] - c0 * gv1[2][h];
      acc1[2][h] += c0 * gv1[1][h] - c1 * gv1[0][h];
    }
    {
      const bf16x8 w7 = WFRAG(7, h);
      const f32x4 o0 = mfma16(w7, b1[0]);
      const f32x4 o1 = mfma16(w7, b1[1]);
      const f32x4 o2 = mfma16(w7, b1[2]);
      const f32x4 tr3 = (o0 * gv1[0][h] + o1 * gv1[1][h] + o2 * gv1[2][h]) * (1.f / 3.f);
      acc2[0][h] += o0 * gv1[0][h] - tr3;
      acc2[1][h] += o0 * gv1[1][h];
      acc2[2][h] += o0 * gv1[2][h];
      acc2[3][h] += o1 * gv1[0][h];
      acc2[4][h] += o1 * gv1[1][h] - tr3;
      acc2[5][h] += o1 * gv1[2][h];
      acc2[6][h] += o2 * gv1[0][h];
      acc2[7][h] += o2 * gv1[1][h];
      acc2[8][h] += o2 * gv1[2][h] - tr3;
    }
    {
      const bf16x8 w8 = WFRAG(8, h);
#pragma unroll
      for (int a = 0; a < 3; ++a)
#pragma unroll
        for (int b = 0; b < 3; ++b)
          acc1[a][h] += mfma16(w8, b2[a * 3 + b]) * gv1[b][h];
    }
  }

  f32x4 gkB[3][2];
#pragma unroll
  for (int j = 0; j < 3; ++j) {
    gkB[j][0] = ntload4(g2p + (3 + j) * 32);
    gkB[j][1] = ntload4(g2p + (3 + j) * 32 + 16);
  }

  f32x4 t2[2];
  t2[0] = mfma16(WFRAG(2, 0), b0);
  t2[1] = mfma16(WFRAG(2, 1), b0);

#define G2ROW_COMPUTE(K, GK)                                                   \
  {                                                                            \
    _Pragma("unroll")                                                          \
    for (int h = 0; h < 2; ++h) {                                              \
      _Pragma("unroll")                                                        \
      for (int j = 0; j < 3; ++j) acc2[(K) * 3 + j][h] += t2[h] * GK[j][h];    \
      {                                                                        \
        const f32x4 vk = mfma16(WFRAG(9, h), b1[(K)]);                         \
        _Pragma("unroll")                                                      \
        for (int j = 0; j < 3; ++j) acc1[j][h] += vk * GK[j][h];               \
      }                                                                        \
      {                                                                        \
        const bf16x8 w10 = WFRAG(10, h);                                       \
        _Pragma("unroll")                                                      \
        for (int j = 0; j < 3; ++j)                                            \
          acc0[h] += mfma16(w10, b2[(K) * 3 + j]) * GK[j][h];                  \
      }                                                                        \
      {                                                                        \
        const bf16x8 w11 = WFRAG(11, h);                                       \
        const f32x4 m0 = mfma16(w11, b2[0 * 3 + (K)]);                         \
        const f32x4 m1 = mfma16(w11, b2[1 * 3 + (K)]);                         \
        const f32x4 m2 = mfma16(w11, b2[2 * 3 + (K)]);                         \
        const f32x4 tk3 =                                                      \
            (m0 * GK[0][h] + m1 * GK[1][h] + m2 * GK[2][h]) * (1.f / 3.f);     \
        acc2[0][h] += m0 * GK[0][h] - tk3;                                     \
        acc2[4][h] += m1 * GK[1][h] - tk3;                                     \
        acc2[8][h] += m2 * GK[2][h] - tk3;                                     \
        const f32x4 s01 = (m0 * GK[1][h] + m1 * GK[0][h]) * 0.5f;              \
        acc2[1][h] += s01; acc2[3][h] += s01;                                  \
        const f32x4 s02 = (m0 * GK[2][h] + m2 * GK[0][h]) * 0.5f;              \
        acc2[2][h] += s02; acc2[6][h] += s02;                                  \
        const f32x4 s12 = (m1 * GK[2][h] + m2 * GK[1][h]) * 0.5f;              \
        acc2[5][h] += s12; acc2[7][h] += s12;                                  \
      }                                                                        \
    }                                                                          \
  }

  G2ROW_COMPUTE(0, gkA)
#pragma unroll
  for (int j = 0; j < 3; ++j) {
    gkA[j][0] = ntload4(g2p + (6 + j) * 32);
    gkA[j][1] = ntload4(g2p + (6 + j) * 32 + 16);
  }
  G2ROW_COMPUTE(1, gkB)
  G2ROW_COMPUTE(2, gkA)
#undef G2ROW_COMPUTE

  float* o0p = out + (long long)e * 32 + col;
  float* o1p = out + (long long)E * 32 + (long long)e * 96 + col;
  float* o2p = out + (long long)E * 128 + (long long)e * 288 + col;
  ntstore4(o0p, acc0[0]);
  ntstore4(o0p + 16, acc0[1]);
#pragma unroll
  for (int s = 0; s < 3; ++s) {
    ntstore4(o1p + s * 32, acc1[s][0]);
    ntstore4(o1p + s * 32 + 16, acc1[s][1]);
  }
#pragma unroll
  for (int s = 0; s < 9; ++s) {
    ntstore4(o2p + s * 32, acc2[s][0]);
    ntstore4(o2p + s * 32 + 16, acc2[s][1]);
  }
#undef WFRAG
}

extern "C" void kernel_launch(void* const* d_in, const int* in_sizes, int n_in,
                              void* d_out, int out_size, void* d_ws, size_t ws_size,
                              hipStream_t stream) {
  const float* h0 = (const float*)d_in[0];
  const float* h1 = (const float*)d_in[1];
  const float* h2 = (const float*)d_in[2];
  const float* g0 = (const float*)d_in[3];
  const float* g1 = (const float*)d_in[4];
  const float* g2 = (const float*)d_in[5];
  const float* Wg = (const float*)d_in[6];
  const int* src = (const int*)d_in[7];  // harness passes integer inputs as int32
  const int E = in_sizes[7];
  const int n0 = in_sizes[0], n1 = in_sizes[1], n2 = in_sizes[2];

  const size_t need = 24576 + (size_t)(n0 + n1 + n2) * 2;
  if (ws_size >= need) {
    __bf16* ws = (__bf16*)d_ws;
    leibniz_prepass<<<2048, 256, 0, stream>>>(h0, h1, h2, Wg, ws, n0, n1, n2);
    // block = 2 edge-tiles x 2 half-waves; pairs share block -> same XCD/L2
    leibniz_half<<<(E + 31) / 32, 256, 0, stream>>>(ws, g0, g1, g2, src,
                                                    (float*)d_out, E, n0, n1);
  } else {
    leibniz_fused<<<(E + 63) / 64, 256, 0, stream>>>(h0, h1, h2, g0, g1, g2,
                                                     Wg, src, (float*)d_out, E);
  }
}